// Round 1
// baseline (105.921 us; speedup 1.0000x reference)
//
#include <hip/hip_runtime.h>

// Chamfer distance, B=8, N=M=8192, D=3, fp32 — fused MFMA formulation.
// Each fp32 split into f16 hi+lo (x = xh+xl, err ~2^-22). K=16 vectors:
//   A(n): [ah0,ah1,ah2, al0,al1,al2, ah0,ah1,ah2, sqh_n,sql_n, 1,1, 0,0,0]
//   B(m): [bh0,bh1,bh2, bh0,bh1,bh2, bl0,bl1,bl2, 1,1, sqh_m,sql_m, 0,0,0]
// with b = -2c (exact scale). One v_mfma_f32_32x32x16_f16 yields a 32x32
// tile of d(n,m) = sq_n + sq_m - 2<a,c> (+O(1e-5)). Each tile feeds BOTH
// mins: over m (dist1, reg fold) and over n (dist2, per-wave LDS plane +
// per-chunk cooperative fold — NO atomics).
// C/D: col=lane&31, row=(reg&3)+8*(reg>>2)+4*(lane>>5)  [HW-verified]
// A/B: row/col=lane&31, k=(lane>>5)*8+j                 [verified: absmax 0]

typedef _Float16 half8 __attribute__((ext_vector_type(8)));
typedef float    f16x  __attribute__((ext_vector_type(16)));

constexpr int B       = 8;
constexpr int NPTS    = 8192;
constexpr int TOTAL   = B * NPTS;        // 65536
constexpr int NSTRIP  = 128;             // n-rows per block (4 waves * 32)
constexpr int NSTRIPS = NPTS / NSTRIP;   // 64
constexpr int MH      = 4;               // m splits per batch
constexpr int MHALF   = NPTS / MH;       // 2048
constexpr int CHUNK   = 512;             // m staged in LDS per chunk
constexpr int NWAVE   = 4;

// min3 tree: min of 16 C-regs (column-min within a lane), 8 issues.
__device__ __forceinline__ float colmin16(const f16x& a)
{
    float m0 = fminf(fminf(a[0],  a[1]),  a[2]);
    float m1 = fminf(fminf(a[3],  a[4]),  a[5]);
    float m2 = fminf(fminf(a[6],  a[7]),  a[8]);
    float m3 = fminf(fminf(a[9],  a[10]), a[11]);
    float m4 = fminf(fminf(a[12], a[13]), a[14]);
    return fminf(fminf(fminf(m0, m1), m2), fminf(fminf(m3, m4), a[15]));
}

// grid (64, 4, 8), block 256 (4 waves x 32 n-rows).
// dist1 (min over m) folded in regs -> d1p[b][mh][n]  (unclamped).
// dist2 (min over n) via per-wave LDS planes, chunk-folded -> d2p[b][strip][m] (clamped).
__global__ __launch_bounds__(256, 5) void chamfer_mfma(
    const float* __restrict__ in1, const float* __restrict__ in2,
    float* __restrict__ d1p, float* __restrict__ d2p, float* __restrict__ out)
{
    const int b     = blockIdx.z;
    const int strip = blockIdx.x;
    const int mh    = blockIdx.y;
    const int wave  = threadIdx.x >> 6;
    const int lane  = threadIdx.x & 63;
    const int col   = lane & 31;
    const int half  = lane >> 5;

    if ((blockIdx.x | blockIdx.y | blockIdx.z) == 0 && threadIdx.x == 0)
        *out = 0.0f;                   // zero accumulator before reduce runs

    __shared__ _Float16 ldsB[CHUNK * 16];      // 16 KiB
    __shared__ float    d2w[NWAVE][CHUNK];     // 8 KiB, per-wave dist2 planes

    // A fragment, packed in-register from raw in1.
    const int nbase = strip * NSTRIP + wave * 32;
    half8 afrag;
    {
        const float* a = in1 + ((size_t)b * NPTS + nbase + col) * 3;
        float x = a[0], y = a[1], z = a[2];
        float sq = fmaf(x, x, fmaf(y, y, z * z));
        _Float16 xh = (_Float16)x, yh = (_Float16)y, zh = (_Float16)z;
        _Float16 xl = (_Float16)(x - (float)xh);
        _Float16 yl = (_Float16)(y - (float)yh);
        _Float16 zl = (_Float16)(z - (float)zh);
        _Float16 sh = (_Float16)sq, sl = (_Float16)(sq - (float)sh);
        half8 lo = {xh, yh, zh, xl, yl, zl, xh, yh};
        half8 hi = {zh, sh, sl, (_Float16)1.f, (_Float16)1.f,
                    (_Float16)0.f, (_Float16)0.f, (_Float16)0.f};
        afrag = half ? hi : lo;
    }

    f16x MN1, zero;
#pragma unroll
    for (int r = 0; r < 16; ++r) { MN1[r] = 1e30f; zero[r] = 0.0f; }

    const float* Craw = in2 + ((size_t)b * NPTS + mh * MHALF) * 3;
    float* d2 = d2p + ((size_t)b * NSTRIPS + strip) * NPTS + mh * MHALF;

    for (int c = 0; c < MHALF / CHUNK; ++c) {
        __syncthreads();    // prev compute done: ldsB free, d2w complete
        // Stage + pack 2 candidates per thread into LDS (B layout).
#pragma unroll
        for (int s = 0; s < 2; ++s) {
            const int i = threadIdx.x + s * 256;
            const float* cp = Craw + (size_t)(c * CHUNK + i) * 3;
            float cx = cp[0], cy = cp[1], cz = cp[2];
            float x = -2.f * cx, y = -2.f * cy, z = -2.f * cz;
            float sq = fmaf(cx, cx, fmaf(cy, cy, cz * cz));
            _Float16 xh = (_Float16)x, yh = (_Float16)y, zh = (_Float16)z;
            _Float16 xl = (_Float16)(x - (float)xh);
            _Float16 yl = (_Float16)(y - (float)yh);
            _Float16 zl = (_Float16)(z - (float)zh);
            _Float16 sh = (_Float16)sq, sl = (_Float16)(sq - (float)sh);
            half8 lo = {xh, yh, zh, xh, yh, zh, xl, yl};
            half8 hi = {zl, (_Float16)1.f, (_Float16)1.f, sh, sl,
                        (_Float16)0.f, (_Float16)0.f, (_Float16)0.f};
            *(half8*)&ldsB[i * 16]     = lo;
            *(half8*)&ldsB[i * 16 + 8] = hi;
        }
        // Fold previous chunk's per-wave d2 planes -> global (disjoint m).
        if (c > 0) {
#pragma unroll
            for (int s = 0; s < 2; ++s) {
                const int i = threadIdx.x + s * 256;
                float v = fminf(fminf(d2w[0][i], d2w[1][i]),
                                fminf(d2w[2][i], d2w[3][i]));
                d2[(c - 1) * CHUNK + i] = fmaxf(v, 0.0f);
            }
        }
        __syncthreads();    // ldsB ready, d2w consumed

#pragma unroll 2
        for (int t = 0; t < CHUNK / 32; t += 2) {
            half8 bfA = *(const half8*)&ldsB[((t    ) * 32 + col) * 16 + half * 8];
            half8 bfB = *(const half8*)&ldsB[((t + 1) * 32 + col) * 16 + half * 8];
            f16x accA = __builtin_amdgcn_mfma_f32_32x32x16_f16(afrag, bfA, zero, 0, 0, 0);
            f16x accB = __builtin_amdgcn_mfma_f32_32x32x16_f16(afrag, bfB, zero, 0, 0, 0);

            // dist1: per-reg running min across m (v_min3 per reg).
#pragma unroll
            for (int r = 0; r < 16; ++r)
                MN1[r] = fminf(fminf(accA[r], accB[r]), MN1[r]);

            // dist2: column-min of each tile, cross-half combine, then all
            // 64 lanes store 64 distinct words (no atomics, no conflicts):
            // half 0 lanes own tile t, half 1 lanes own tile t+1.
            float vA = colmin16(accA);
            float vB = colmin16(accB);
            vA = fminf(vA, __shfl_xor(vA, 32, 64));
            vB = fminf(vB, __shfl_xor(vB, 32, 64));
            d2w[wave][t * 32 + lane] = half ? vB : vA;
        }
    }
    __syncthreads();
    // Fold the last chunk's d2 planes.
#pragma unroll
    for (int s = 0; s < 2; ++s) {
        const int i = threadIdx.x + s * 256;
        float v = fminf(fminf(d2w[0][i], d2w[1][i]),
                        fminf(d2w[2][i], d2w[3][i]));
        d2[(MHALF / CHUNK - 1) * CHUNK + i] = fmaxf(v, 0.0f);
    }

    // dist1: butterfly min across the 32 cols of each half, lane 0 of each
    // half writes its 16 rows: row = (r&3) + 8*(r>>2) + 4*half.
#pragma unroll
    for (int m = 1; m <= 16; m <<= 1)
#pragma unroll
        for (int r = 0; r < 16; ++r)
            MN1[r] = fminf(MN1[r], __shfl_xor(MN1[r], m, 64));
    if (col == 0) {
        float* d1 = d1p + ((size_t)b * MH + mh) * NPTS + nbase;
#pragma unroll
        for (int r = 0; r < 16; ++r)
            d1[(r & 3) + 8 * (r >> 2) + 4 * half] = MN1[r];
    }
}

// One thread per 4 m's: fold 64 d2 strip-planes + 4 d1 planes (float4),
// sum, wave-reduce, atomicAdd(out, sum/TOTAL). 256 blocks x 64 threads
// so all 256 CUs pull HBM concurrently.
__global__ __launch_bounds__(64) void reduce_kernel(
    const float* __restrict__ d1p, const float* __restrict__ d2p,
    float* __restrict__ out)
{
    int g  = blockIdx.x * 64 + threadIdx.x;       // [0, TOTAL/4)
    int b  = g >> 11;
    int mq = g & 2047;                            // float4 index within batch

    const float4* p2 = (const float4*)(d2p + (size_t)b * NSTRIPS * NPTS) + mq;
    float4 v2 = p2[0];
#pragma unroll 8
    for (int s = 1; s < NSTRIPS; ++s) {
        float4 t = p2[(size_t)s * (NPTS / 4)];
        v2.x = fminf(v2.x, t.x); v2.y = fminf(v2.y, t.y);
        v2.z = fminf(v2.z, t.z); v2.w = fminf(v2.w, t.w);
    }
    const float4* p1 = (const float4*)(d1p + (size_t)b * MH * NPTS) + mq;
    float4 a = p1[0];
#pragma unroll
    for (int s = 1; s < MH; ++s) {
        float4 t = p1[(size_t)s * (NPTS / 4)];
        a.x = fminf(a.x, t.x); a.y = fminf(a.y, t.y);
        a.z = fminf(a.z, t.z); a.w = fminf(a.w, t.w);
    }
    float v = fmaxf(a.x, 0.0f) + fmaxf(a.y, 0.0f)
            + fmaxf(a.z, 0.0f) + fmaxf(a.w, 0.0f)
            + v2.x + v2.y + v2.z + v2.w;

#pragma unroll
    for (int off = 32; off; off >>= 1)
        v += __shfl_down(v, off, 64);
    if (threadIdx.x == 0)
        atomicAdd(out, v * (1.0f / (float)TOTAL));
}

extern "C" void kernel_launch(void* const* d_in, const int* in_sizes, int n_in,
                              void* d_out, int out_size, void* d_ws, size_t ws_size,
                              hipStream_t stream)
{
    const float* in1 = (const float*)d_in[0];
    const float* in2 = (const float*)d_in[1];
    float* out = (float*)d_out;

    char* ws = (char*)d_ws;
    float* d1p = (float*)ws;                                  // MH*TOTAL*4 = 1 MiB
    float* d2p = (float*)(ws + (size_t)MH * TOTAL * 4);       // 64*TOTAL*4 = 16 MiB

    chamfer_mfma<<<dim3(NSTRIPS, MH, B), 256, 0, stream>>>(
        in1, in2, d1p, d2p, out);
    reduce_kernel<<<TOTAL / 4 / 64, 64, 0, stream>>>(d1p, d2p, out);
}

// Round 2
// 97.454 us; speedup vs baseline: 1.0869x; 1.0869x over previous
//
#include <hip/hip_runtime.h>

// Chamfer distance, B=8, N=M=8192, D=3, fp32 — fused MFMA formulation.
// Each fp32 split into f16 hi+lo (x = xh+xl, err ~2^-22). K=16 vectors:
//   A(n): [ah0,ah1,ah2, al0,al1,al2, ah0,ah1,ah2, sqh_n,sql_n, 1,1, 0,0,0]
//   B(m): [bh0,bh1,bh2, bh0,bh1,bh2, bl0,bl1,bl2, 1,1, sqh_m,sql_m, 0,0,0]
// with b = -2c (exact scale). One v_mfma_f32_32x32x16_f16 yields a 32x32
// tile of d(n,m) = sq_n + sq_m - 2<a,c> (+O(1e-5)). Each tile feeds BOTH
// mins: over m (dist1, reg fold) and over n (dist2, per-wave LDS plane,
// chunk-folded — NO atomics).
// C/D: col=lane&31, row=(reg&3)+8*(reg>>2)+4*(lane>>5)  [HW-verified]
// A/B: row/col=lane&31, k=(lane>>5)*8+j                 [verified: absmax 0]
//
// LDS layout (new): B-frag for (cand i, part p) lives at element
//   (i>>5)*512 + p*256 + (i&31)*8   (byte: (i>>5)*1024 + p*512 + (i&31)*16)
// so lane l of tile t reads at byte t*1024 + l*16 — LINEAR in lane:
// conflict-free ds_read_b128 with compile-time offset, vs the old
// col*32+half*16 stride-32B pattern (8-way bank conflict, round-1 PMC).

typedef _Float16 half8 __attribute__((ext_vector_type(8)));
typedef float    f16x  __attribute__((ext_vector_type(16)));

constexpr int B       = 8;
constexpr int NPTS    = 8192;
constexpr int TOTAL   = B * NPTS;        // 65536
constexpr int NSTRIP  = 256;             // n-rows per block (8 waves * 32)
constexpr int NSTRIPS = NPTS / NSTRIP;   // 32
constexpr int MH      = 2;               // m splits per batch
constexpr int MHALF   = NPTS / MH;       // 4096
constexpr int CHUNK   = 512;             // m staged in LDS per chunk
constexpr int NWAVE   = 8;

// min3 tree: min of 16 C-regs (column-min within a lane), 8 issues.
__device__ __forceinline__ float colmin16(const f16x& a)
{
    float m0 = fminf(fminf(a[0],  a[1]),  a[2]);
    float m1 = fminf(fminf(a[3],  a[4]),  a[5]);
    float m2 = fminf(fminf(a[6],  a[7]),  a[8]);
    float m3 = fminf(fminf(a[9],  a[10]), a[11]);
    float m4 = fminf(fminf(a[12], a[13]), a[14]);
    return fminf(fminf(fminf(m0, m1), m2), fminf(fminf(m3, m4), a[15]));
}

// grid (32, 2, 8), block 512 (8 waves x 32 n-rows).
// dist1 (min over m) folded in regs -> d1p[b][mh][n]  (unclamped).
// dist2 (min over n) per-wave LDS planes, chunk-folded -> d2p[b][strip][m] (clamped).
__global__ __launch_bounds__(512, 4) void chamfer_mfma(
    const float* __restrict__ in1, const float* __restrict__ in2,
    float* __restrict__ d1p, float* __restrict__ d2p, float* __restrict__ out)
{
    const int b     = blockIdx.z;
    const int strip = blockIdx.x;
    const int mh    = blockIdx.y;
    const int wave  = threadIdx.x >> 6;
    const int lane  = threadIdx.x & 63;
    const int col   = lane & 31;
    const int half  = lane >> 5;

    if ((blockIdx.x | blockIdx.y | blockIdx.z) == 0 && threadIdx.x == 0)
        *out = 0.0f;                   // zero accumulator before reduce runs

    __shared__ _Float16 ldsB[CHUNK * 16];      // 16 KiB
    __shared__ float    d2w[NWAVE][CHUNK];     // 16 KiB, per-wave dist2 planes

    // A fragment, packed in-register from raw in1.
    const int nbase = strip * NSTRIP + wave * 32;
    half8 afrag;
    {
        const float* a = in1 + ((size_t)b * NPTS + nbase + col) * 3;
        float x = a[0], y = a[1], z = a[2];
        float sq = fmaf(x, x, fmaf(y, y, z * z));
        _Float16 xh = (_Float16)x, yh = (_Float16)y, zh = (_Float16)z;
        _Float16 xl = (_Float16)(x - (float)xh);
        _Float16 yl = (_Float16)(y - (float)yh);
        _Float16 zl = (_Float16)(z - (float)zh);
        _Float16 sh = (_Float16)sq, sl = (_Float16)(sq - (float)sh);
        half8 lo = {xh, yh, zh, xl, yl, zl, xh, yh};
        half8 hi = {zh, sh, sl, (_Float16)1.f, (_Float16)1.f,
                    (_Float16)0.f, (_Float16)0.f, (_Float16)0.f};
        afrag = half ? hi : lo;
    }

    f16x MN1, zacc;
#pragma unroll
    for (int r = 0; r < 16; ++r) { MN1[r] = 1e30f; zacc[r] = 0.0f; }

    const float* Craw = in2 + ((size_t)b * NPTS + mh * MHALF) * 3;
    float* d2 = d2p + ((size_t)b * NSTRIPS + strip) * NPTS + mh * MHALF;

    for (int c = 0; c < MHALF / CHUNK; ++c) {
        __syncthreads();    // prev compute done: ldsB free, d2w complete
        // Stage + pack one candidate per thread into LDS (permuted layout).
        {
            const int i = threadIdx.x;
            const float* cp = Craw + (size_t)(c * CHUNK + i) * 3;
            float cx = cp[0], cy = cp[1], cz = cp[2];
            float x = -2.f * cx, y = -2.f * cy, z = -2.f * cz;
            float sq = fmaf(cx, cx, fmaf(cy, cy, cz * cz));
            _Float16 xh = (_Float16)x, yh = (_Float16)y, zh = (_Float16)z;
            _Float16 xl = (_Float16)(x - (float)xh);
            _Float16 yl = (_Float16)(y - (float)yh);
            _Float16 zl = (_Float16)(z - (float)zh);
            _Float16 sh = (_Float16)sq, sl = (_Float16)(sq - (float)sh);
            half8 lo = {xh, yh, zh, xh, yh, zh, xl, yl};
            half8 hi = {zl, (_Float16)1.f, (_Float16)1.f, sh, sl,
                        (_Float16)0.f, (_Float16)0.f, (_Float16)0.f};
            *(half8*)&ldsB[(i >> 5) * 512 + (i & 31) * 8]       = lo;
            *(half8*)&ldsB[(i >> 5) * 512 + 256 + (i & 31) * 8] = hi;
        }
        // Fold previous chunk's per-wave d2 planes -> global (disjoint m).
        if (c > 0) {
            const int i = threadIdx.x;
            float v = d2w[0][i];
#pragma unroll
            for (int w = 1; w < NWAVE; ++w) v = fminf(v, d2w[w][i]);
            d2[(c - 1) * CHUNK + i] = fmaxf(v, 0.0f);
        }
        __syncthreads();    // ldsB ready, d2w consumed

#pragma unroll 2
        for (int t = 0; t < CHUNK / 32; t += 2) {
            half8 bfA = *(const half8*)&ldsB[ t      * 512 + lane * 8];
            half8 bfB = *(const half8*)&ldsB[(t + 1) * 512 + lane * 8];
            f16x accA = __builtin_amdgcn_mfma_f32_32x32x16_f16(afrag, bfA, zacc, 0, 0, 0);
            f16x accB = __builtin_amdgcn_mfma_f32_32x32x16_f16(afrag, bfB, zacc, 0, 0, 0);

            // dist1: per-reg running min across m (v_min3 per reg).
#pragma unroll
            for (int r = 0; r < 16; ++r)
                MN1[r] = fminf(fminf(accA[r], accB[r]), MN1[r]);

            // dist2: column-min of each tile, cross-half combine, then all
            // 64 lanes store 64 distinct d2w words (no atomics, no dup):
            // half 0 lanes own tile t, half 1 lanes own tile t+1.
            float vA = colmin16(accA);
            float vB = colmin16(accB);
            vA = fminf(vA, __shfl_xor(vA, 32, 64));
            vB = fminf(vB, __shfl_xor(vB, 32, 64));
            d2w[wave][(t + half) * 32 + col] = half ? vB : vA;
        }
    }
    __syncthreads();
    // Fold the last chunk's d2 planes.
    {
        const int i = threadIdx.x;
        float v = d2w[0][i];
#pragma unroll
        for (int w = 1; w < NWAVE; ++w) v = fminf(v, d2w[w][i]);
        d2[(MHALF / CHUNK - 1) * CHUNK + i] = fmaxf(v, 0.0f);
    }

    // dist1: butterfly min across the 32 cols of each half, lane 0 of each
    // half writes its 16 rows: row = (r&3) + 8*(r>>2) + 4*half.
#pragma unroll
    for (int m = 1; m <= 16; m <<= 1)
#pragma unroll
        for (int r = 0; r < 16; ++r)
            MN1[r] = fminf(MN1[r], __shfl_xor(MN1[r], m, 64));
    if (col == 0) {
        float* d1 = d1p + ((size_t)b * MH + mh) * NPTS + nbase;
#pragma unroll
        for (int r = 0; r < 16; ++r)
            d1[(r & 3) + 8 * (r >> 2) + 4 * half] = MN1[r];
    }
}

// One thread per 4 m's: fold 32 d2 strip-planes + 2 d1 planes (float4),
// sum, wave-reduce, atomicAdd(out, sum/TOTAL). 256 blocks x 64 threads
// so all 256 CUs pull HBM concurrently.
__global__ __launch_bounds__(64) void reduce_kernel(
    const float* __restrict__ d1p, const float* __restrict__ d2p,
    float* __restrict__ out)
{
    int g  = blockIdx.x * 64 + threadIdx.x;       // [0, TOTAL/4)
    int b  = g >> 11;
    int mq = g & 2047;                            // float4 index within batch

    const float4* p2 = (const float4*)(d2p + (size_t)b * NSTRIPS * NPTS) + mq;
    float4 v2 = p2[0];
#pragma unroll 8
    for (int s = 1; s < NSTRIPS; ++s) {
        float4 t = p2[(size_t)s * (NPTS / 4)];
        v2.x = fminf(v2.x, t.x); v2.y = fminf(v2.y, t.y);
        v2.z = fminf(v2.z, t.z); v2.w = fminf(v2.w, t.w);
    }
    const float4* p1 = (const float4*)(d1p + (size_t)b * MH * NPTS) + mq;
    float4 a = p1[0];
#pragma unroll
    for (int s = 1; s < MH; ++s) {
        float4 t = p1[(size_t)s * (NPTS / 4)];
        a.x = fminf(a.x, t.x); a.y = fminf(a.y, t.y);
        a.z = fminf(a.z, t.z); a.w = fminf(a.w, t.w);
    }
    float v = fmaxf(a.x, 0.0f) + fmaxf(a.y, 0.0f)
            + fmaxf(a.z, 0.0f) + fmaxf(a.w, 0.0f)
            + v2.x + v2.y + v2.z + v2.w;

#pragma unroll
    for (int off = 32; off; off >>= 1)
        v += __shfl_down(v, off, 64);
    if (threadIdx.x == 0)
        atomicAdd(out, v * (1.0f / (float)TOTAL));
}

extern "C" void kernel_launch(void* const* d_in, const int* in_sizes, int n_in,
                              void* d_out, int out_size, void* d_ws, size_t ws_size,
                              hipStream_t stream)
{
    const float* in1 = (const float*)d_in[0];
    const float* in2 = (const float*)d_in[1];
    float* out = (float*)d_out;

    char* ws = (char*)d_ws;
    float* d1p = (float*)ws;                                  // MH*TOTAL*4 = 512 KiB
    float* d2p = (float*)(ws + (size_t)MH * TOTAL * 4);       // 32*TOTAL*4 = 8 MiB

    chamfer_mfma<<<dim3(NSTRIPS, MH, B), 512, 0, stream>>>(
        in1, in2, d1p, d2p, out);
    reduce_kernel<<<TOTAL / 4 / 64, 64, 0, stream>>>(d1p, d2p, out);
}